// Round 9
// baseline (514.271 us; speedup 1.0000x reference)
//
#include <hip/hip_runtime.h>

// B=8, S=4096, E=256, H=4, DK=64. Tokens = B*S = 32768.
// Round-10: ABLATION round. Six falsified theories; fused invariant at 42-43us
// across all structural variants. This launch decomposes the cost into phases,
// each as its own dispatch (NREP-looped so every one clears the ~42us fill
// threshold in the top-5 table; per-rep = dur/NREP):
//   v1_stage     : x->LDS staging only                         (NREP=24)
//   v2_qkv_one   : + QKV proj, single W copy (status-quo path) (NREP=6)
//   v3_qkv_repl  : + QKV proj, 8 XCD-local W copies (b&7)      (NREP=6)
//   v4_full_repl : full pipeline, replicated W, out->scratch   (NREP=3)
//   fused_attn   : real kernel (replicated W) -> out           (correctness)
// zreg() laundering blocks LICM of per-rep loads; asm sinks block DCE.
// dur_us is sacrificed this round for phase attribution.

typedef __bf16 bf16x8 __attribute__((ext_vector_type(8)));
typedef __bf16 bf16x4 __attribute__((ext_vector_type(4)));
typedef float f32x4 __attribute__((ext_vector_type(4)));

#define LDW 264   // LDS row stride in bf16 elems (256+8 pad)
#define MROWS 32  // tokens per block
#define XSW(row, col) ((col) ^ ((((row) >> 3) & 1) << 4))
#define CELEM (512 * 512)   // 262144 bf16 per Wpk copy (512 KB)

// ---------- pack 8 copies of W; copy c written by blocks with blockIdx&7==c
// (assumed round-robin XCD dispatch -> copy c is dirty/home in XCD c's L2) ----
__global__ void pack_wfrag8(const float* __restrict__ Wq, const float* __restrict__ Wk,
                            const float* __restrict__ Wv, const float* __restrict__ Wo,
                            __bf16* __restrict__ Wpk) {
  const int c = blockIdx.x & 7;
  const int f = blockIdx.x >> 3;        // 0..511
  const int lane = threadIdx.x;
  const int kk = f & 7, g16 = (f >> 3) & 15, p = f >> 7;
  const float* W = (p == 0) ? Wq : (p == 1) ? Wk : (p == 2) ? Wv : Wo;
  const int lh = lane & 15, lq = lane >> 4;
  const int n = g16 * 16 + lh, k0 = kk * 32 + lq * 8;
  const float4 s0 = *(const float4*)&W[n * 256 + k0];
  const float4 s1 = *(const float4*)&W[n * 256 + k0 + 4];
  bf16x8 r;
  r[0] = (__bf16)s0.x; r[1] = (__bf16)s0.y; r[2] = (__bf16)s0.z; r[3] = (__bf16)s0.w;
  r[4] = (__bf16)s1.x; r[5] = (__bf16)s1.y; r[6] = (__bf16)s1.z; r[7] = (__bf16)s1.w;
  *(bf16x8*)&Wpk[(size_t)c * CELEM + (size_t)f * 512 + lane * 8] = r;
}

// laundered zero: defeats LICM of loop-invariant loads inside NREP loops
__device__ __forceinline__ int zreg() { int z = 0; asm volatile("" : "+v"(z)); return z; }

#define MFMA(d, a, b) d = __builtin_amdgcn_mfma_f32_16x16x32_bf16(a, b, d, 0, 0, 0)

#define ZERO_ACC22(acc)                                          \
  _Pragma("unroll")                                              \
  for (int mf_ = 0; mf_ < 2; ++mf_)                              \
    _Pragma("unroll")                                            \
    for (int nf_ = 0; nf_ < 2; ++nf_)                            \
      acc[mf_][nf_] = (f32x4){0.f, 0.f, 0.f, 0.f};

// ---------- shared device pieces (R8-verified bodies) ----------
__device__ __forceinline__ void stage_x(const float* __restrict__ x, __bf16* xs,
                                        int tid, int tok0, int zoff) {
  const float4* xg = (const float4*)(x + (size_t)tok0 * 256);
  #pragma unroll
  for (int i = 0; i < 4; ++i) {
    int idx = i * 512 + tid + zoff;
    int row = idx >> 6;
    int c4  = idx & 63;
    float4 v = xg[idx];
    bf16x4 pk;
    pk[0] = (__bf16)v.x; pk[1] = (__bf16)v.y; pk[2] = (__bf16)v.z; pk[3] = (__bf16)v.w;
    *(bf16x4*)&xs[row * LDW + XSW(row, c4 * 4)] = pk;
  }
}

__device__ __forceinline__ void store_cd32(__bf16* __restrict__ buf, const f32x4 acc[2][2],
                                           const float* __restrict__ bias,
                                           int n0, int lh, int lq) {
  #pragma unroll
  for (int nf = 0; nf < 2; ++nf) {
    int col = n0 + nf * 16 + lh;
    float bb = bias[col];
    #pragma unroll
    for (int mf = 0; mf < 2; ++mf) {
      int r = mf * 16 + lq * 4;
      #pragma unroll
      for (int j = 0; j < 4; ++j)
        buf[(r + j) * LDW + XSW(r + j, col)] = (__bf16)(acc[mf][nf][j] + bb);
    }
  }
}

__device__ __forceinline__ void qkv_pass(const __bf16* __restrict__ xs, __bf16* qs,
                                         __bf16* ksh, __bf16* vs,
                                         const __bf16* wlq, const __bf16* wlk,
                                         const __bf16* wlv,
                                         const float* bq, const float* bk, const float* bv,
                                         int n0, int lh, int lq) {
  f32x4 aq[2][2], ak[2][2], av[2][2];
  ZERO_ACC22(aq);
  ZERO_ACC22(ak);
  ZERO_ACC22(av);
  const int xsw = ((lh >> 3) & 1) << 4;
  const __bf16* ap = xs + lh * LDW;
  #pragma unroll
  for (int kk = 0; kk < 8; ++kk) {
    bf16x8 wq0 = *(const bf16x8*)(wlq + (0 * 8 + kk) * 512);
    bf16x8 wq1 = *(const bf16x8*)(wlq + (1 * 8 + kk) * 512);
    bf16x8 wk0 = *(const bf16x8*)(wlk + (0 * 8 + kk) * 512);
    bf16x8 wk1 = *(const bf16x8*)(wlk + (1 * 8 + kk) * 512);
    bf16x8 wv0 = *(const bf16x8*)(wlv + (0 * 8 + kk) * 512);
    bf16x8 wv1 = *(const bf16x8*)(wlv + (1 * 8 + kk) * 512);
    const int c = (kk * 32 + lq * 8) ^ xsw;
    bf16x8 a0 = *(const bf16x8*)(ap +  0 * LDW + c);
    bf16x8 a1 = *(const bf16x8*)(ap + 16 * LDW + c);
    MFMA(aq[0][0], a0, wq0); MFMA(aq[1][0], a1, wq0);
    MFMA(aq[0][1], a0, wq1); MFMA(aq[1][1], a1, wq1);
    MFMA(ak[0][0], a0, wk0); MFMA(ak[1][0], a1, wk0);
    MFMA(ak[0][1], a0, wk1); MFMA(ak[1][1], a1, wk1);
    MFMA(av[0][0], a0, wv0); MFMA(av[1][0], a1, wv0);
    MFMA(av[0][1], a0, wv1); MFMA(av[1][1], a1, wv1);
  }
  store_cd32(qs, aq, bq, n0, lh, lq);
  store_cd32(ksh, ak, bk, n0, lh, lq);
  store_cd32(vs, av, bv, n0, lh, lq);
}

__device__ __forceinline__ void sm_ymix(const __bf16* qs, const __bf16* ksh,
                                        const __bf16* vs, __bf16* ys, int tid) {
  const int lane = tid & 63;
  const int m   = tid >> 4;
  const int sub = tid & 15;
  const int h   = sub & 3;
  const int kh  = sub >> 2;
  const int dof = kh * 16;
  const int msw = ((m >> 3) & 1) << 4;
  float d0 = 0.f, d1 = 0.f, d2 = 0.f, d3 = 0.f;
  #pragma unroll
  for (int i = 0; i < 2; ++i) {
    bf16x8 qv = *(const bf16x8*)&qs[m * LDW + ((h * 64 + dof + i * 8) ^ msw)];
    bf16x8 k0 = *(const bf16x8*)&ksh[m * LDW + ((  0 + dof + i * 8) ^ msw)];
    bf16x8 k1 = *(const bf16x8*)&ksh[m * LDW + (( 64 + dof + i * 8) ^ msw)];
    bf16x8 k2 = *(const bf16x8*)&ksh[m * LDW + ((128 + dof + i * 8) ^ msw)];
    bf16x8 k3 = *(const bf16x8*)&ksh[m * LDW + ((192 + dof + i * 8) ^ msw)];
    #pragma unroll
    for (int j = 0; j < 8; ++j) {
      float qf = (float)qv[j];
      d0 += qf * (float)k0[j];
      d1 += qf * (float)k1[j];
      d2 += qf * (float)k2[j];
      d3 += qf * (float)k3[j];
    }
  }
  d0 += __shfl_xor(d0, 4);  d0 += __shfl_xor(d0, 8);
  d1 += __shfl_xor(d1, 4);  d1 += __shfl_xor(d1, 8);
  d2 += __shfl_xor(d2, 4);  d2 += __shfl_xor(d2, 8);
  d3 += __shfl_xor(d3, 4);  d3 += __shfl_xor(d3, 8);
  d0 *= 0.125f; d1 *= 0.125f; d2 *= 0.125f; d3 *= 0.125f;
  float mx = fmaxf(fmaxf(d0, d1), fmaxf(d2, d3));
  float e0 = expf(d0 - mx), e1 = expf(d1 - mx), e2 = expf(d2 - mx), e3 = expf(d3 - mx);
  float inv = 1.0f / (e0 + e1 + e2 + e3);
  float pg0 = e0 * inv, pg1 = e1 * inv, pg2 = e2 * inv, pg3 = e3 * inv;

  const int src = (lane & 48) | (sub >> 2);
  float p0 = __shfl(pg0, src);
  float p1 = __shfl(pg1, src);
  float p2 = __shfl(pg2, src);
  float p3 = __shfl(pg3, src);

  const int hy = sub >> 2;
  const int c0 = (sub & 3) * 16;
  #pragma unroll
  for (int i = 0; i < 2; ++i) {
    int c = c0 + i * 8;
    bf16x8 v0 = *(const bf16x8*)&vs[m * LDW + ((  0 + c) ^ msw)];
    bf16x8 v1 = *(const bf16x8*)&vs[m * LDW + (( 64 + c) ^ msw)];
    bf16x8 v2 = *(const bf16x8*)&vs[m * LDW + ((128 + c) ^ msw)];
    bf16x8 v3 = *(const bf16x8*)&vs[m * LDW + ((192 + c) ^ msw)];
    bf16x8 yv;
    #pragma unroll
    for (int j = 0; j < 8; ++j) {
      float f = p0 * (float)v0[j] + p1 * (float)v1[j]
              + p2 * (float)v2[j] + p3 * (float)v3[j];
      yv[j] = (__bf16)f;
    }
    *(bf16x8*)&ys[m * LDW + ((hy * 64 + c) ^ msw)] = yv;
  }
}

__device__ __forceinline__ void out_gemm(const __bf16* __restrict__ ys,
                                         const __bf16* __restrict__ wlo,
                                         const float* __restrict__ bo,
                                         float* __restrict__ dst,
                                         int n0, int lh, int lq, int tok0) {
  f32x4 acc[2][2];
  ZERO_ACC22(acc);
  const int xsw = ((lh >> 3) & 1) << 4;
  const __bf16* ap = ys + lh * LDW;
  #pragma unroll
  for (int kk = 0; kk < 8; ++kk) {
    bf16x8 w0 = *(const bf16x8*)(wlo + (0 * 8 + kk) * 512);
    bf16x8 w1 = *(const bf16x8*)(wlo + (1 * 8 + kk) * 512);
    const int c = (kk * 32 + lq * 8) ^ xsw;
    bf16x8 a0 = *(const bf16x8*)(ap +  0 * LDW + c);
    bf16x8 a1 = *(const bf16x8*)(ap + 16 * LDW + c);
    MFMA(acc[0][0], a0, w0); MFMA(acc[1][0], a1, w0);
    MFMA(acc[0][1], a0, w1); MFMA(acc[1][1], a1, w1);
  }
  #pragma unroll
  for (int nf = 0; nf < 2; ++nf) {
    int col = n0 + nf * 16 + lh;
    float bb = bo[col];
    #pragma unroll
    for (int mf = 0; mf < 2; ++mf) {
      int rbase = tok0 + mf * 16 + lq * 4;
      #pragma unroll
      for (int j = 0; j < 4; ++j)
        dst[(size_t)(rbase + j) * 256 + col] = acc[mf][nf][j] + bb;
    }
  }
}

// ---------- V1: staging only ----------
__launch_bounds__(512, 4)
__global__ void v1_stage(const float* __restrict__ x, int nrep) {
  __shared__ __bf16 xs[MROWS * LDW];
  __shared__ __bf16 qs[MROWS * LDW];
  __shared__ __bf16 ksh[MROWS * LDW];
  __shared__ __bf16 vs[MROWS * LDW];
  const int tid = threadIdx.x;
  const int tok0 = blockIdx.x * MROWS;
  for (int r = 0; r < nrep; ++r) {
    stage_x(x, xs, tid, tok0, zreg());
    __syncthreads();
    float s = (float)xs[tid] + (float)qs[tid] + (float)ksh[tid] + (float)vs[tid];
    asm volatile("" :: "v"(s));
    __syncthreads();
  }
}

// ---------- V2: stage + QKV, single W copy (status-quo W path) ----------
__launch_bounds__(512, 4)
__global__ void v2_qkv_one(const float* __restrict__ x, const __bf16* __restrict__ Wpk,
                           const float* __restrict__ bq, const float* __restrict__ bk,
                           const float* __restrict__ bv, int nrep) {
  __shared__ __bf16 xs[MROWS * LDW];
  __shared__ __bf16 qs[MROWS * LDW];
  __shared__ __bf16 ksh[MROWS * LDW];
  __shared__ __bf16 vs[MROWS * LDW];
  const int tid = threadIdx.x, lane = tid & 63, w = tid >> 6;
  const int lh = lane & 15, lq = lane >> 4, n0 = w * 32;
  const int tok0 = blockIdx.x * MROWS;
  for (int r = 0; r < nrep; ++r) {
    stage_x(x, xs, tid, tok0, zreg());
    __syncthreads();
    const __bf16* base = Wpk + zreg();              // copy 0 only
    const __bf16* wlq = base + (size_t)(0 * 128 + w * 16) * 512 + lane * 8;
    const __bf16* wlk = base + (size_t)(1 * 128 + w * 16) * 512 + lane * 8;
    const __bf16* wlv = base + (size_t)(2 * 128 + w * 16) * 512 + lane * 8;
    qkv_pass(xs, qs, ksh, vs, wlq, wlk, wlv, bq, bk, bv, n0, lh, lq);
    __syncthreads();
    float s = (float)qs[tid] + (float)ksh[tid] + (float)vs[tid];
    asm volatile("" :: "v"(s));
    __syncthreads();
  }
}

// ---------- V3: stage + QKV, XCD-local W copy (blockIdx&7) ----------
__launch_bounds__(512, 4)
__global__ void v3_qkv_repl(const float* __restrict__ x, const __bf16* __restrict__ Wpk,
                            const float* __restrict__ bq, const float* __restrict__ bk,
                            const float* __restrict__ bv, int nrep) {
  __shared__ __bf16 xs[MROWS * LDW];
  __shared__ __bf16 qs[MROWS * LDW];
  __shared__ __bf16 ksh[MROWS * LDW];
  __shared__ __bf16 vs[MROWS * LDW];
  const int tid = threadIdx.x, lane = tid & 63, w = tid >> 6;
  const int lh = lane & 15, lq = lane >> 4, n0 = w * 32;
  const int tok0 = blockIdx.x * MROWS;
  const size_t cbase = (size_t)(blockIdx.x & 7) * CELEM;
  for (int r = 0; r < nrep; ++r) {
    stage_x(x, xs, tid, tok0, zreg());
    __syncthreads();
    const __bf16* base = Wpk + cbase + zreg();
    const __bf16* wlq = base + (size_t)(0 * 128 + w * 16) * 512 + lane * 8;
    const __bf16* wlk = base + (size_t)(1 * 128 + w * 16) * 512 + lane * 8;
    const __bf16* wlv = base + (size_t)(2 * 128 + w * 16) * 512 + lane * 8;
    qkv_pass(xs, qs, ksh, vs, wlq, wlk, wlv, bq, bk, bv, n0, lh, lq);
    __syncthreads();
    float s = (float)qs[tid] + (float)ksh[tid] + (float)vs[tid];
    asm volatile("" :: "v"(s));
    __syncthreads();
  }
}

// ---------- V4: full pipeline, replicated W, output to scratch ----------
__launch_bounds__(512, 4)
__global__ void v4_full_repl(const float* __restrict__ x, const __bf16* __restrict__ Wpk,
                             const float* __restrict__ bq, const float* __restrict__ bk,
                             const float* __restrict__ bv, const float* __restrict__ bo,
                             float* __restrict__ dump, int nrep) {
  __shared__ __bf16 xs[MROWS * LDW];
  __shared__ __bf16 qs[MROWS * LDW];
  __shared__ __bf16 ksh[MROWS * LDW];
  __shared__ __bf16 vs[MROWS * LDW];
  const int tid = threadIdx.x, lane = tid & 63, w = tid >> 6;
  const int lh = lane & 15, lq = lane >> 4, n0 = w * 32;
  const int tok0 = blockIdx.x * MROWS;
  const size_t cbase = (size_t)(blockIdx.x & 7) * CELEM;
  for (int r = 0; r < nrep; ++r) {
    stage_x(x, xs, tid, tok0, zreg());
    __syncthreads();
    const __bf16* base = Wpk + cbase + zreg();
    const __bf16* wlq = base + (size_t)(0 * 128 + w * 16) * 512 + lane * 8;
    const __bf16* wlk = base + (size_t)(1 * 128 + w * 16) * 512 + lane * 8;
    const __bf16* wlv = base + (size_t)(2 * 128 + w * 16) * 512 + lane * 8;
    qkv_pass(xs, qs, ksh, vs, wlq, wlk, wlv, bq, bk, bv, n0, lh, lq);
    __syncthreads();
    sm_ymix(qs, ksh, vs, xs, tid);
    __syncthreads();
    const __bf16* wlo = base + (size_t)(3 * 128 + w * 16) * 512 + lane * 8;
    out_gemm(xs, wlo, bo, dump, n0, lh, lq, tok0);
    __syncthreads();
  }
}

// ---------- real kernel: R8 structure + replicated W, writes out ----------
__launch_bounds__(512, 4)
__global__ void fused_attn(const float* __restrict__ x, const __bf16* __restrict__ Wpk,
                           const float* __restrict__ bq, const float* __restrict__ bk,
                           const float* __restrict__ bv, const float* __restrict__ bo,
                           float* __restrict__ out) {
  __shared__ __bf16 xs[MROWS * LDW];
  __shared__ __bf16 qs[MROWS * LDW];
  __shared__ __bf16 ksh[MROWS * LDW];
  __shared__ __bf16 vs[MROWS * LDW];
  const int tid = threadIdx.x, lane = tid & 63, w = tid >> 6;
  const int lh = lane & 15, lq = lane >> 4, n0 = w * 32;
  const int tok0 = blockIdx.x * MROWS;
  const __bf16* base = Wpk + (size_t)(blockIdx.x & 7) * CELEM;
  const __bf16* wlq = base + (size_t)(0 * 128 + w * 16) * 512 + lane * 8;
  const __bf16* wlk = base + (size_t)(1 * 128 + w * 16) * 512 + lane * 8;
  const __bf16* wlv = base + (size_t)(2 * 128 + w * 16) * 512 + lane * 8;
  const __bf16* wlo = base + (size_t)(3 * 128 + w * 16) * 512 + lane * 8;

  stage_x(x, xs, tid, tok0, 0);
  __syncthreads();
  qkv_pass(xs, qs, ksh, vs, wlq, wlk, wlv, bq, bk, bv, n0, lh, lq);
  __syncthreads();
  sm_ymix(qs, ksh, vs, xs, tid);
  __syncthreads();
  out_gemm(xs, wlo, bo, out, n0, lh, lq, tok0);
}

extern "C" void kernel_launch(void* const* d_in, const int* in_sizes, int n_in,
                              void* d_out, int out_size, void* d_ws, size_t ws_size,
                              hipStream_t stream) {
  const float* x  = (const float*)d_in[0];
  const float* Wq = (const float*)d_in[1];
  const float* bq = (const float*)d_in[2];
  const float* Wk = (const float*)d_in[3];
  const float* bk = (const float*)d_in[4];
  const float* Wv = (const float*)d_in[5];
  const float* bv = (const float*)d_in[6];
  const float* Wo = (const float*)d_in[7];
  const float* bo = (const float*)d_in[8];
  float* out = (float*)d_out;
  __bf16* Wpk = (__bf16*)d_ws;                          // 8 copies x 512 KB = 4 MB
  float* dump = (float*)((char*)d_ws + (8u << 20));     // 32 MB scratch at ws+8MB

  pack_wfrag8<<<dim3(4096), dim3(64), 0, stream>>>(Wq, Wk, Wv, Wo, Wpk);
  v1_stage  <<<dim3(1024), dim3(512), 0, stream>>>(x, 24);
  v2_qkv_one<<<dim3(1024), dim3(512), 0, stream>>>(x, Wpk, bq, bk, bv, 6);
  v3_qkv_repl<<<dim3(1024), dim3(512), 0, stream>>>(x, Wpk, bq, bk, bv, 6);
  v4_full_repl<<<dim3(1024), dim3(512), 0, stream>>>(x, Wpk, bq, bk, bv, bo, dump, 3);
  fused_attn<<<dim3(1024), dim3(512), 0, stream>>>(x, Wpk, bq, bk, bv, bo, out);
}

// Round 15
// 128.161 us; speedup vs baseline: 4.0127x; 4.0127x over previous
//
#include <hip/hip_runtime.h>

// B=8, S=4096, E=256, H=4, DK=64. Tokens = B*S = 32768.
// Round-11 RESUBMIT x5 (acquisition timeouts; never measured). Coalesced
// epilogue. R10 ablation: v4(full)-v3(qkv) >= 27us/rep -> output path
// dominates. Cause: 16 scattered 4B stores/thread into poisoned (HBM-cold)
// out lines -> 64B partial segments -> L2 RMW allocate (v4: +17MB fetch /
// +21MB write beyond payload). Fix: stage fp32 out-tile in LDS (dead
// qs/ksh/vs region, stride 260 -> conflict-free), then copy with full-line
// float4 stores (wave = 1KB rows). No warm_l2 (falsified R8); keep 8x
// replicated W (cheap). Else = R8 structure (2 blocks/CU, 3 barriers).

typedef __bf16 bf16x8 __attribute__((ext_vector_type(8)));
typedef __bf16 bf16x4 __attribute__((ext_vector_type(4)));
typedef float f32x4 __attribute__((ext_vector_type(4)));

#define LDW 264   // LDS row stride in bf16 elems (256+8 pad)
#define MROWS 32  // tokens per block
#define XSW(row, col) ((col) ^ ((((row) >> 3) & 1) << 4))
#define CELEM (512 * 512)   // 262144 bf16 per Wpk copy (512 KB)
#define OSTR 260            // fp32 out-stage row stride (260*4B: +4 pad)

// ---------- pack 8 copies of W; copy c written by blocks with blockIdx&7==c ----
__global__ void pack_wfrag8(const float* __restrict__ Wq, const float* __restrict__ Wk,
                            const float* __restrict__ Wv, const float* __restrict__ Wo,
                            __bf16* __restrict__ Wpk) {
  const int c = blockIdx.x & 7;
  const int f = blockIdx.x >> 3;        // 0..511
  const int lane = threadIdx.x;
  const int kk = f & 7, g16 = (f >> 3) & 15, p = f >> 7;
  const float* W = (p == 0) ? Wq : (p == 1) ? Wk : (p == 2) ? Wv : Wo;
  const int lh = lane & 15, lq = lane >> 4;
  const int n = g16 * 16 + lh, k0 = kk * 32 + lq * 8;
  const float4 s0 = *(const float4*)&W[n * 256 + k0];
  const float4 s1 = *(const float4*)&W[n * 256 + k0 + 4];
  bf16x8 r;
  r[0] = (__bf16)s0.x; r[1] = (__bf16)s0.y; r[2] = (__bf16)s0.z; r[3] = (__bf16)s0.w;
  r[4] = (__bf16)s1.x; r[5] = (__bf16)s1.y; r[6] = (__bf16)s1.z; r[7] = (__bf16)s1.w;
  *(bf16x8*)&Wpk[(size_t)c * CELEM + (size_t)f * 512 + lane * 8] = r;
}

#define MFMA(d, a, b) d = __builtin_amdgcn_mfma_f32_16x16x32_bf16(a, b, d, 0, 0, 0)

#define ZERO_ACC22(acc)                                          \
  _Pragma("unroll")                                              \
  for (int mf_ = 0; mf_ < 2; ++mf_)                              \
    _Pragma("unroll")                                            \
    for (int nf_ = 0; nf_ < 2; ++nf_)                            \
      acc[mf_][nf_] = (f32x4){0.f, 0.f, 0.f, 0.f};

__device__ __forceinline__ void store_cd32(__bf16* __restrict__ buf, const f32x4 acc[2][2],
                                           const float* __restrict__ bias,
                                           int n0, int lh, int lq) {
  #pragma unroll
  for (int nf = 0; nf < 2; ++nf) {
    int col = n0 + nf * 16 + lh;
    float bb = bias[col];
    #pragma unroll
    for (int mf = 0; mf < 2; ++mf) {
      int r = mf * 16 + lq * 4;
      #pragma unroll
      for (int j = 0; j < 4; ++j)
        buf[(r + j) * LDW + XSW(r + j, col)] = (__bf16)(acc[mf][nf][j] + bb);
    }
  }
}

__launch_bounds__(512, 4)
__global__ void fused_attn(const float* __restrict__ x, const __bf16* __restrict__ Wpk,
                           const float* __restrict__ bq, const float* __restrict__ bk,
                           const float* __restrict__ bv, const float* __restrict__ bo,
                           float* __restrict__ out) {
  // one LDS pool, pointers carved; qs/ksh/vs region is reused as fp32 out-stage
  __shared__ __bf16 lds[4 * MROWS * LDW];            // 67.6 KB -> 2 blocks/CU
  __bf16* xs  = lds;                                  // x tile, then Y
  __bf16* qs  = lds + 1 * MROWS * LDW;                // Q
  __bf16* ksh = lds + 2 * MROWS * LDW;                // K
  __bf16* vs  = lds + 3 * MROWS * LDW;                // V
  float*  ostage = (float*)(lds + 1 * MROWS * LDW);   // 33.3KB of the 50.7KB region

  const int tid  = threadIdx.x;          // 0..511
  const int lane = tid & 63;
  const int w    = tid >> 6;             // wave 0..7
  const int lh   = lane & 15;
  const int lq   = lane >> 4;
  const int n0   = w * 32;
  const int tok0 = blockIdx.x * MROWS;

  // ---- stage x tile: lane-contiguous float4 loads -> bf16 swizzled LDS ----
  const float4* xg = (const float4*)(x + (size_t)tok0 * 256);
  #pragma unroll
  for (int i = 0; i < 4; ++i) {
    int idx = i * 512 + tid;           // float4 id, 0..2047
    int row = idx >> 6;
    int c4  = idx & 63;
    float4 v = xg[idx];
    bf16x4 pk;
    pk[0] = (__bf16)v.x; pk[1] = (__bf16)v.y; pk[2] = (__bf16)v.z; pk[3] = (__bf16)v.w;
    *(bf16x4*)&xs[row * LDW + XSW(row, c4 * 4)] = pk;
  }

  // XCD-local packed-weight copy; frag_id = p*128 + (2w+nf)*8 + kk
  const __bf16* base = Wpk + (size_t)(blockIdx.x & 7) * CELEM;
  const __bf16* wlq = base + (size_t)(0 * 128 + w * 16) * 512 + lane * 8;
  const __bf16* wlk = base + (size_t)(1 * 128 + w * 16) * 512 + lane * 8;
  const __bf16* wlv = base + (size_t)(2 * 128 + w * 16) * 512 + lane * 8;
  const __bf16* wlo = base + (size_t)(3 * 128 + w * 16) * 512 + lane * 8;

  __syncthreads();                       // x staged

  // ---- merged Q+K+V projection: one A-read pass, W streamed per-kk ----
  {
    f32x4 aq[2][2], ak[2][2], av[2][2];
    ZERO_ACC22(aq);
    ZERO_ACC22(ak);
    ZERO_ACC22(av);
    const int xsw = ((lh >> 3) & 1) << 4;
    const __bf16* ap = xs + lh * LDW;
    #pragma unroll
    for (int kk = 0; kk < 8; ++kk) {
      bf16x8 wq0 = *(const bf16x8*)(wlq + (0 * 8 + kk) * 512);
      bf16x8 wq1 = *(const bf16x8*)(wlq + (1 * 8 + kk) * 512);
      bf16x8 wk0 = *(const bf16x8*)(wlk + (0 * 8 + kk) * 512);
      bf16x8 wk1 = *(const bf16x8*)(wlk + (1 * 8 + kk) * 512);
      bf16x8 wv0 = *(const bf16x8*)(wlv + (0 * 8 + kk) * 512);
      bf16x8 wv1 = *(const bf16x8*)(wlv + (1 * 8 + kk) * 512);
      const int c = (kk * 32 + lq * 8) ^ xsw;
      bf16x8 a0 = *(const bf16x8*)(ap +  0 * LDW + c);
      bf16x8 a1 = *(const bf16x8*)(ap + 16 * LDW + c);
      MFMA(aq[0][0], a0, wq0); MFMA(aq[1][0], a1, wq0);
      MFMA(aq[0][1], a0, wq1); MFMA(aq[1][1], a1, wq1);
      MFMA(ak[0][0], a0, wk0); MFMA(ak[1][0], a1, wk0);
      MFMA(ak[0][1], a0, wk1); MFMA(ak[1][1], a1, wk1);
      MFMA(av[0][0], a0, wv0); MFMA(av[1][0], a1, wv0);
      MFMA(av[0][1], a0, wv1); MFMA(av[1][1], a1, wv1);
    }
    store_cd32(qs, aq, bq, n0, lh, lq);
    store_cd32(ksh, ak, bk, n0, lh, lq);
    store_cd32(vs, av, bv, n0, lh, lq);
  }
  __syncthreads();   // Q,K,V visible; xs reads complete

  // ---- fused softmax + y-mix: 16 threads/token, shfl-only ----
  {
    const int m   = tid >> 4;
    const int sub = tid & 15;
    const int h   = sub & 3;
    const int kh  = sub >> 2;
    const int dof = kh * 16;
    const int msw = ((m >> 3) & 1) << 4;
    float d0 = 0.f, d1 = 0.f, d2 = 0.f, d3 = 0.f;
    #pragma unroll
    for (int i = 0; i < 2; ++i) {
      bf16x8 qv = *(const bf16x8*)&qs[m * LDW + ((h * 64 + dof + i * 8) ^ msw)];
      bf16x8 k0 = *(const bf16x8*)&ksh[m * LDW + ((  0 + dof + i * 8) ^ msw)];
      bf16x8 k1 = *(const bf16x8*)&ksh[m * LDW + (( 64 + dof + i * 8) ^ msw)];
      bf16x8 k2 = *(const bf16x8*)&ksh[m * LDW + ((128 + dof + i * 8) ^ msw)];
      bf16x8 k3 = *(const bf16x8*)&ksh[m * LDW + ((192 + dof + i * 8) ^ msw)];
      #pragma unroll
      for (int j = 0; j < 8; ++j) {
        float qf = (float)qv[j];
        d0 += qf * (float)k0[j];
        d1 += qf * (float)k1[j];
        d2 += qf * (float)k2[j];
        d3 += qf * (float)k3[j];
      }
    }
    d0 += __shfl_xor(d0, 4);  d0 += __shfl_xor(d0, 8);
    d1 += __shfl_xor(d1, 4);  d1 += __shfl_xor(d1, 8);
    d2 += __shfl_xor(d2, 4);  d2 += __shfl_xor(d2, 8);
    d3 += __shfl_xor(d3, 4);  d3 += __shfl_xor(d3, 8);
    d0 *= 0.125f; d1 *= 0.125f; d2 *= 0.125f; d3 *= 0.125f;  // 1/sqrt(64)
    float mx = fmaxf(fmaxf(d0, d1), fmaxf(d2, d3));
    float e0 = expf(d0 - mx), e1 = expf(d1 - mx), e2 = expf(d2 - mx), e3 = expf(d3 - mx);
    float inv = 1.0f / (e0 + e1 + e2 + e3);
    float pg0 = e0 * inv, pg1 = e1 * inv, pg2 = e2 * inv, pg3 = e3 * inv;

    const int src = (lane & 48) | (sub >> 2);
    float p0 = __shfl(pg0, src);
    float p1 = __shfl(pg1, src);
    float p2 = __shfl(pg2, src);
    float p3 = __shfl(pg3, src);

    const int hy = sub >> 2;
    const int c0 = (sub & 3) * 16;
    #pragma unroll
    for (int i = 0; i < 2; ++i) {
      int c = c0 + i * 8;
      bf16x8 v0 = *(const bf16x8*)&vs[m * LDW + ((  0 + c) ^ msw)];
      bf16x8 v1 = *(const bf16x8*)&vs[m * LDW + (( 64 + c) ^ msw)];
      bf16x8 v2 = *(const bf16x8*)&vs[m * LDW + ((128 + c) ^ msw)];
      bf16x8 v3 = *(const bf16x8*)&vs[m * LDW + ((192 + c) ^ msw)];
      bf16x8 yv;
      #pragma unroll
      for (int j = 0; j < 8; ++j) {
        float f = p0 * (float)v0[j] + p1 * (float)v1[j]
                + p2 * (float)v2[j] + p3 * (float)v3[j];
        yv[j] = (__bf16)f;
      }
      *(bf16x8*)&xs[m * LDW + ((hy * 64 + c) ^ msw)] = yv;   // Y over dead x
    }
  }
  __syncthreads();   // Y visible; qs/ksh/vs now dead -> ostage may reuse

  // ---- output GEMM: compute -> LDS fp32 stage -> coalesced float4 out ----
  {
    f32x4 acc[2][2];
    ZERO_ACC22(acc);
    const int xsw = ((lh >> 3) & 1) << 4;
    const __bf16* ap = xs + lh * LDW;
    #pragma unroll
    for (int kk = 0; kk < 8; ++kk) {
      bf16x8 w0 = *(const bf16x8*)(wlo + (0 * 8 + kk) * 512);
      bf16x8 w1 = *(const bf16x8*)(wlo + (1 * 8 + kk) * 512);
      const int c = (kk * 32 + lq * 8) ^ xsw;
      bf16x8 a0 = *(const bf16x8*)(ap +  0 * LDW + c);
      bf16x8 a1 = *(const bf16x8*)(ap + 16 * LDW + c);
      MFMA(acc[0][0], a0, w0); MFMA(acc[1][0], a1, w0);
      MFMA(acc[0][1], a0, w1); MFMA(acc[1][1], a1, w1);
    }
    // bias + stage to LDS (stride OSTR=260 floats)
    #pragma unroll
    for (int nf = 0; nf < 2; ++nf) {
      int col = n0 + nf * 16 + lh;
      float bb = bo[col];
      #pragma unroll
      for (int mf = 0; mf < 2; ++mf) {
        int r = mf * 16 + lq * 4;
        #pragma unroll
        for (int j = 0; j < 4; ++j)
          ostage[(r + j) * OSTR + col] = acc[mf][nf][j] + bb;
      }
    }
    __syncthreads();   // tile staged
    // each wave writes full 1KB rows: lane-contiguous float4, no RMW
    float4* og = (float4*)(out + (size_t)tok0 * 256);
    #pragma unroll
    for (int i = 0; i < 4; ++i) {
      int idx = i * 512 + tid;          // 0..2047
      int row = idx >> 6;
      int c4  = idx & 63;
      float4 v = *(const float4*)&ostage[row * OSTR + c4 * 4];
      og[(size_t)row * 64 + c4] = v;
    }
  }
}

extern "C" void kernel_launch(void* const* d_in, const int* in_sizes, int n_in,
                              void* d_out, int out_size, void* d_ws, size_t ws_size,
                              hipStream_t stream) {
  const float* x  = (const float*)d_in[0];
  const float* Wq = (const float*)d_in[1];
  const float* bq = (const float*)d_in[2];
  const float* Wk = (const float*)d_in[3];
  const float* bk = (const float*)d_in[4];
  const float* Wv = (const float*)d_in[5];
  const float* bv = (const float*)d_in[6];
  const float* Wo = (const float*)d_in[7];
  const float* bo = (const float*)d_in[8];
  float* out = (float*)d_out;
  __bf16* Wpk = (__bf16*)d_ws;   // 8 copies x 512 KB = 4 MB

  pack_wfrag8<<<dim3(4096), dim3(64), 0, stream>>>(Wq, Wk, Wv, Wo, Wpk);
  fused_attn<<<dim3(1024), dim3(512), 0, stream>>>(x, Wpk, bq, bk, bv, bo, out);
}